// Round 4
// baseline (46.032 us; speedup 1.0000x reference)
//
#include <hip/hip_runtime.h>
#include <hip/hip_bf16.h>

#define NB 32
#define NP 4096
#define NC 128
#define ND 128
#define TP 128            // points per block
#define EPSV 1e-16f

typedef __attribute__((ext_vector_type(8))) short short8;
typedef __attribute__((ext_vector_type(4))) float f32x4;

__device__ __forceinline__ unsigned short f2bf(float f) {
  __hip_bfloat16 h = __float2bfloat16(f);
  return *reinterpret_cast<unsigned short*>(&h);
}

// LDS byte-offset swizzle: row-major [row][128 bf16] with XOR of (row&7)<<4.
__device__ __forceinline__ int swz(int row, int kbyte) {
  return (row * 256 + kbyte) ^ ((row & 7) << 4);
}

// Pre-kernel: pre-swizzled bf16 codes^T images ([d][c]) for the 32 gathered
// records -> d_ws. Dedups the f32->bf16 transpose and enables zero-VALU DMA
// staging in the main kernel.
__global__ void cc_pre(const int* __restrict__ indices,
                       const float* __restrict__ codes,
                       unsigned char* __restrict__ ws) {
  const int b = blockIdx.x;
  const int rec = indices[b];
  const float* cb = codes + (size_t)rec * (NC * ND);
  unsigned char* wb = ws + (size_t)b * (NC * ND * 2);
  const int tid = threadIdx.x;        // 1024 threads
  const int d = tid & 127;
  const int cq0 = tid >> 7;           // 0..7
  #pragma unroll
  for (int it = 0; it < 4; ++it) {
    const int c = (cq0 + it * 8) * 4;
    unsigned long long v = 0;
    #pragma unroll
    for (int j = 0; j < 4; ++j)
      v |= (unsigned long long)f2bf(cb[(size_t)(c + j) * ND + d]) << (16 * j);
    *(unsigned long long*)(wb + swz(d, c * 2)) = v;
  }
}

template<bool PRE>
__global__ __launch_bounds__(256, 2) void cc_main(
    const int* __restrict__ indices,
    const float* __restrict__ qp,       // (B,P,3)
    const float* __restrict__ cpos,     // (R,C,3)
    const float* __restrict__ codes,    // (R,C,D)
    const void* __restrict__ dsp,       // dist_scale scalar
    const unsigned char* __restrict__ wsc, // pre-swizzled bf16 cT images
    float* __restrict__ out_qc,         // (B,P,D)
    float* __restrict__ out_sq,         // (B,P,C)
    float* __restrict__ out_wt) {       // (B,P,C)
  __shared__ __align__(16) unsigned char wT[TP * NC * 2];   // W  [p][c] 32KB
  __shared__ __align__(16) unsigned char cT[ND * NC * 2];   // C^T[d][c] 32KB

  const int tid = threadIdx.x;
  const int lane = tid & 63;
  const int wv = tid >> 6;
  const int g = lane >> 4;            // point-within-quad
  const int l16 = lane & 15;
  const int c0 = l16 * 8;             // this lane's 8 codes (phase 1)
  const int b = blockIdx.x >> 5;
  const int p0 = (blockIdx.x & 31) * TP;
  const int rec = indices[b];

  const int si = ((const int*)dsp)[0];
  const float sv = (si > 0 && si < 1000) ? (float)si : ((const float*)dsp)[0];

  // ---- hoist per-lane global reads (independent, single latency)
  const float* pb = cpos + ((size_t)rec * NC + c0) * 3;
  float px[8], py[8], pz[8];
  #pragma unroll
  for (int j = 0; j < 8; ++j) {
    px[j] = pb[j * 3 + 0]; py[j] = pb[j * 3 + 1]; pz[j] = pb[j * 3 + 2];
  }

  const size_t rowbase = (size_t)b * NP + p0;
  float qx[8], qy[8], qz[8];
  #pragma unroll
  for (int it = 0; it < 8; ++it) {
    const int p = it * 16 + wv * 4 + g;
    const float* q = qp + (rowbase + p) * 3;
    qx[it] = q[0]; qy[it] = q[1]; qz[it] = q[2];
  }

  // ---- cT staging: DMA issued after q/pos loads; drains at the barrier,
  // fully overlapped with phase 1.
  if (PRE) {
    const unsigned char* src = wsc + (size_t)b * (NC * ND * 2);
    #pragma unroll
    for (int it = 0; it < 8; ++it) {
      const int off = (wv * 8 + it) * 1024;
      __builtin_amdgcn_global_load_lds(
          (const __attribute__((address_space(1))) void*)(src + off + lane * 16),
          (__attribute__((address_space(3))) void*)(cT + off),
          16, 0, 0);
    }
  } else {
    const float* cb = codes + (size_t)rec * (NC * ND);
    #pragma unroll
    for (int it = 0; it < 16; ++it) {
      int i = tid * 4 + it * 1024;
      float4 v = *reinterpret_cast<const float4*>(cb + i);
      int c = i >> 7, d0 = i & 127;
      float vv[4] = {v.x, v.y, v.z, v.w};
      #pragma unroll
      for (int j = 0; j < 4; ++j)
        *(unsigned short*)(cT + swz(d0 + j, c * 2)) = f2bf(vv[j]);
    }
  }

  // ---- phase 1: 4 points per wave in flight; lane owns 8 codes.
  const bool s2 = (sv == 2.0f);
  #pragma unroll
  for (int it = 0; it < 8; ++it) {
    const int p = it * 16 + wv * 4 + g;
    float dd[8], wu[8];
    #pragma unroll
    for (int j = 0; j < 8; ++j) {
      const float dx = qx[it] - px[j], dy = qy[it] - py[j], dz = qz[it] - pz[j];
      dd[j] = fmaf(dx, dx, fmaf(dy, dy, dz * dz)) + EPSV;
    }
    if (s2) {
      #pragma unroll
      for (int j = 0; j < 8; ++j) wu[j] = __builtin_amdgcn_rcpf(dd[j]);
    } else {
      #pragma unroll
      for (int j = 0; j < 8; ++j) wu[j] = __powf(dd[j], -0.5f * sv);
    }
    float s = ((wu[0] + wu[1]) + (wu[2] + wu[3])) + ((wu[4] + wu[5]) + (wu[6] + wu[7]));
    s += __shfl_xor(s, 1); s += __shfl_xor(s, 2);
    s += __shfl_xor(s, 4); s += __shfl_xor(s, 8);   // within 16-lane group
    const float inv = __builtin_amdgcn_rcpf(s);

    f32x4 dlo, dhi, wlo, whi;
    #pragma unroll
    for (int j = 0; j < 4; ++j) {
      dlo[j] = dd[j]; dhi[j] = dd[j + 4];
      wlo[j] = wu[j] * inv; whi[j] = wu[j + 4] * inv;
    }
    const size_t rb = (rowbase + p) * (size_t)NC + c0;
    *(f32x4*)(out_sq + rb) = dlo;
    *(f32x4*)(out_sq + rb + 4) = dhi;
    *(f32x4*)(out_wt + rb) = wlo;
    *(f32x4*)(out_wt + rb + 4) = whi;

    short8 w8;
    #pragma unroll
    for (int j = 0; j < 4; ++j) { w8[j] = (short)f2bf(wlo[j]); w8[j + 4] = (short)f2bf(whi[j]); }
    *(short8*)(wT + swz(p, c0 * 2)) = w8;           // one ds_write_b128
  }

  __syncthreads();   // drains wT writes + cT DMA (overlapped with phase 1)

  // ---- phase 2: MFMA einsum, SWAPPED operands: D[d][p]. A-frag = cT row (d),
  // B-frag = wT row (p). Lane's 4 acc regs span 4 consecutive d at fixed p
  // -> qc stores are global_store_dwordx4 (validated numerically in round 3).
  const int kg = lane >> 4;
  f32x4 acc[2][8];
  #pragma unroll
  for (int pi = 0; pi < 2; ++pi)
    #pragma unroll
    for (int mi = 0; mi < 8; ++mi)
      acc[pi][mi] = (f32x4){0.f, 0.f, 0.f, 0.f};

  const int pr0 = wv * 32 + l16;       // this lane's two points (n-dim)
  #pragma unroll
  for (int kk = 0; kk < NC; kk += 32) {
    const int kb = (kk + kg * 8) * 2;
    const short8 b0 = *(const short8*)(wT + swz(pr0, kb));
    const short8 b1 = *(const short8*)(wT + swz(pr0 + 16, kb));
    #pragma unroll
    for (int mi = 0; mi < 8; ++mi) {
      const short8 a8 = *(const short8*)(cT + swz(mi * 16 + l16, kb));
      acc[0][mi] = __builtin_amdgcn_mfma_f32_16x16x32_bf16(a8, b0, acc[0][mi], 0, 0, 0);
      acc[1][mi] = __builtin_amdgcn_mfma_f32_16x16x32_bf16(a8, b1, acc[1][mi], 0, 0, 0);
    }
  }

  // D layout: col(=p-offset) = lane&15, row(=d-offset) = (lane>>4)*4 + reg
  float* q0 = out_qc + (rowbase + pr0) * (size_t)ND + kg * 4;
  float* q1 = out_qc + (rowbase + pr0 + 16) * (size_t)ND + kg * 4;
  #pragma unroll
  for (int mi = 0; mi < 8; ++mi) {
    *(f32x4*)(q0 + mi * 16) = acc[0][mi];
    *(f32x4*)(q1 + mi * 16) = acc[1][mi];
  }

  (void)codes;
}

extern "C" void kernel_launch(void* const* d_in, const int* in_sizes, int n_in,
                              void* d_out, int out_size, void* d_ws, size_t ws_size,
                              hipStream_t stream) {
  const int* indices = (const int*)d_in[0];
  const float* qp = (const float*)d_in[1];
  const float* cpos = (const float*)d_in[2];
  const float* codes = (const float*)d_in[3];
  const void* dsp = d_in[4];

  float* out = (float*)d_out;
  float* qc = out;                                   // (B,P,D)
  float* sq = qc + (size_t)NB * NP * ND;             // (B,P,C)
  float* wt = sq + (size_t)NB * NP * NC;             // (B,P,C)

  const size_t ws_need = (size_t)NB * NC * ND * 2;   // 1 MiB
  dim3 grid(NB * (NP / TP));
  if (ws_size >= ws_need) {
    cc_pre<<<dim3(NB), dim3(1024), 0, stream>>>(indices, codes, (unsigned char*)d_ws);
    cc_main<true><<<grid, 256, 0, stream>>>(indices, qp, cpos, codes, dsp,
                                            (const unsigned char*)d_ws, qc, sq, wt);
  } else {
    cc_main<false><<<grid, 256, 0, stream>>>(indices, qp, cpos, codes, dsp,
                                             nullptr, qc, sq, wt);
  }
}

// Round 5
// 45.331 us; speedup vs baseline: 1.0155x; 1.0155x over previous
//
#include <hip/hip_runtime.h>
#include <hip/hip_bf16.h>

#define NB 32
#define NP 4096
#define NC 128
#define ND 128
#define TP 128            // points per block
#define EPSV 1e-16f

typedef __attribute__((ext_vector_type(8))) short short8;
typedef __attribute__((ext_vector_type(4))) float f32x4;

__device__ __forceinline__ unsigned short f2bf(float f) {
  __hip_bfloat16 h = __float2bfloat16(f);
  return *reinterpret_cast<unsigned short*>(&h);
}

// LDS byte-offset swizzle: row-major [row][128 bf16] with XOR of (row&7)<<4.
// All accesses use aligned sizes <=16B, and the XOR only moves bits 4-6, so
// aligned 8B/16B accesses stay contiguous after swizzling.
__device__ __forceinline__ int swz(int row, int kbyte) {
  return (row * 256 + kbyte) ^ ((row & 7) << 4);
}

// Pre-kernel (widened, round 5): pre-swizzled bf16 codes^T images ([d][c]) for
// the 32 gathered records -> d_ws. 256 blocks (8 per record, 16 d-rows each),
// 256 threads: per thread 8 lane-coalesced scalar loads + one 16B store.
// Cuts the serial prefix ~6x vs the 32-block version.
__global__ void cc_pre(const int* __restrict__ indices,
                       const float* __restrict__ codes,
                       unsigned char* __restrict__ ws) {
  const int b = blockIdx.x >> 3;
  const int chunk = blockIdx.x & 7;
  const int rec = indices[b];
  const float* cb = codes + (size_t)rec * (NC * ND);
  unsigned char* wb = ws + (size_t)b * (NC * ND * 2);
  const int tid = threadIdx.x;        // 256 threads
  const int d = chunk * 16 + (tid & 15);
  const int c0 = (tid >> 4) * 8;      // 8 consecutive codes
  short8 v;
  #pragma unroll
  for (int j = 0; j < 8; ++j)
    v[j] = (short)f2bf(cb[(size_t)(c0 + j) * ND + d]);
  *(short8*)(wb + swz(d, c0 * 2)) = v;
}

template<bool PRE>
__global__ __launch_bounds__(256, 2) void cc_main(
    const int* __restrict__ indices,
    const float* __restrict__ qp,       // (B,P,3)
    const float* __restrict__ cpos,     // (R,C,3)
    const float* __restrict__ codes,    // (R,C,D)
    const void* __restrict__ dsp,       // dist_scale scalar
    const unsigned char* __restrict__ wsc, // pre-swizzled bf16 cT images
    float* __restrict__ out_qc,         // (B,P,D)
    float* __restrict__ out_sq,         // (B,P,C)
    float* __restrict__ out_wt) {       // (B,P,C)
  __shared__ __align__(16) unsigned char wT[TP * NC * 2];   // W  [p][c] 32KB
  __shared__ __align__(16) unsigned char cT[ND * NC * 2];   // C^T[d][c] 32KB

  const int tid = threadIdx.x;
  const int lane = tid & 63;
  const int wv = tid >> 6;
  const int g = lane >> 4;            // point-within-quad
  const int l16 = lane & 15;
  const int c0 = l16 * 8;             // this lane's 8 codes (phase 1)
  const int b = blockIdx.x >> 5;
  const int p0 = (blockIdx.x & 31) * TP;
  const int rec = indices[b];

  const int si = ((const int*)dsp)[0];
  const float sv = (si > 0 && si < 1000) ? (float)si : ((const float*)dsp)[0];

  // ---- hoist per-lane global reads (independent, single latency)
  const float* pb = cpos + ((size_t)rec * NC + c0) * 3;
  float px[8], py[8], pz[8];
  #pragma unroll
  for (int j = 0; j < 8; ++j) {
    px[j] = pb[j * 3 + 0]; py[j] = pb[j * 3 + 1]; pz[j] = pb[j * 3 + 2];
  }

  const size_t rowbase = (size_t)b * NP + p0;
  float qx[8], qy[8], qz[8];
  #pragma unroll
  for (int it = 0; it < 8; ++it) {
    const int p = it * 16 + wv * 4 + g;
    const float* q = qp + (rowbase + p) * 3;
    qx[it] = q[0]; qy[it] = q[1]; qz[it] = q[2];
  }

  // ---- cT staging: DMA issued after q/pos loads; drains at the barrier,
  // fully overlapped with phase 1.
  if (PRE) {
    const unsigned char* src = wsc + (size_t)b * (NC * ND * 2);
    #pragma unroll
    for (int it = 0; it < 8; ++it) {
      const int off = (wv * 8 + it) * 1024;
      __builtin_amdgcn_global_load_lds(
          (const __attribute__((address_space(1))) void*)(src + off + lane * 16),
          (__attribute__((address_space(3))) void*)(cT + off),
          16, 0, 0);
    }
  } else {
    const float* cb = codes + (size_t)rec * (NC * ND);
    #pragma unroll
    for (int it = 0; it < 16; ++it) {
      int i = tid * 4 + it * 1024;
      float4 v = *reinterpret_cast<const float4*>(cb + i);
      int c = i >> 7, d0 = i & 127;
      float vv[4] = {v.x, v.y, v.z, v.w};
      #pragma unroll
      for (int j = 0; j < 4; ++j)
        *(unsigned short*)(cT + swz(d0 + j, c * 2)) = f2bf(vv[j]);
    }
  }

  // ---- phase 1: 4 points per wave in flight; lane owns 8 codes.
  const bool s2 = (sv == 2.0f);
  #pragma unroll
  for (int it = 0; it < 8; ++it) {
    const int p = it * 16 + wv * 4 + g;
    float dd[8], wu[8];
    #pragma unroll
    for (int j = 0; j < 8; ++j) {
      const float dx = qx[it] - px[j], dy = qy[it] - py[j], dz = qz[it] - pz[j];
      dd[j] = fmaf(dx, dx, fmaf(dy, dy, dz * dz)) + EPSV;
    }
    if (s2) {
      #pragma unroll
      for (int j = 0; j < 8; ++j) wu[j] = __builtin_amdgcn_rcpf(dd[j]);
    } else {
      #pragma unroll
      for (int j = 0; j < 8; ++j) wu[j] = __powf(dd[j], -0.5f * sv);
    }
    float s = ((wu[0] + wu[1]) + (wu[2] + wu[3])) + ((wu[4] + wu[5]) + (wu[6] + wu[7]));
    s += __shfl_xor(s, 1); s += __shfl_xor(s, 2);
    s += __shfl_xor(s, 4); s += __shfl_xor(s, 8);   // within 16-lane group
    const float inv = __builtin_amdgcn_rcpf(s);

    f32x4 dlo, dhi, wlo, whi;
    #pragma unroll
    for (int j = 0; j < 4; ++j) {
      dlo[j] = dd[j]; dhi[j] = dd[j + 4];
      wlo[j] = wu[j] * inv; whi[j] = wu[j + 4] * inv;
    }
    const size_t rb = (rowbase + p) * (size_t)NC + c0;
    *(f32x4*)(out_sq + rb) = dlo;
    *(f32x4*)(out_sq + rb + 4) = dhi;
    *(f32x4*)(out_wt + rb) = wlo;
    *(f32x4*)(out_wt + rb + 4) = whi;

    short8 w8;
    #pragma unroll
    for (int j = 0; j < 4; ++j) { w8[j] = (short)f2bf(wlo[j]); w8[j + 4] = (short)f2bf(whi[j]); }
    *(short8*)(wT + swz(p, c0 * 2)) = w8;           // one ds_write_b128
  }

  __syncthreads();   // drains wT writes + cT DMA (overlapped with phase 1)

  // ---- phase 2: MFMA einsum, SWAPPED operands: D[d][p]. A-frag = cT row (d),
  // B-frag = wT row (p). Lane's 4 acc regs span 4 consecutive d at fixed p
  // -> qc stores are global_store_dwordx4 (validated numerically in round 3/4).
  const int kg = lane >> 4;
  f32x4 acc[2][8];
  #pragma unroll
  for (int pi = 0; pi < 2; ++pi)
    #pragma unroll
    for (int mi = 0; mi < 8; ++mi)
      acc[pi][mi] = (f32x4){0.f, 0.f, 0.f, 0.f};

  const int pr0 = wv * 32 + l16;       // this lane's two points (n-dim)
  #pragma unroll
  for (int kk = 0; kk < NC; kk += 32) {
    const int kb = (kk + kg * 8) * 2;
    const short8 b0 = *(const short8*)(wT + swz(pr0, kb));
    const short8 b1 = *(const short8*)(wT + swz(pr0 + 16, kb));
    #pragma unroll
    for (int mi = 0; mi < 8; ++mi) {
      const short8 a8 = *(const short8*)(cT + swz(mi * 16 + l16, kb));
      acc[0][mi] = __builtin_amdgcn_mfma_f32_16x16x32_bf16(a8, b0, acc[0][mi], 0, 0, 0);
      acc[1][mi] = __builtin_amdgcn_mfma_f32_16x16x32_bf16(a8, b1, acc[1][mi], 0, 0, 0);
    }
  }

  // D layout: col(=p-offset) = lane&15, row(=d-offset) = (lane>>4)*4 + reg
  float* q0 = out_qc + (rowbase + pr0) * (size_t)ND + kg * 4;
  float* q1 = out_qc + (rowbase + pr0 + 16) * (size_t)ND + kg * 4;
  #pragma unroll
  for (int mi = 0; mi < 8; ++mi) {
    *(f32x4*)(q0 + mi * 16) = acc[0][mi];
    *(f32x4*)(q1 + mi * 16) = acc[1][mi];
  }

  (void)codes;
}

extern "C" void kernel_launch(void* const* d_in, const int* in_sizes, int n_in,
                              void* d_out, int out_size, void* d_ws, size_t ws_size,
                              hipStream_t stream) {
  const int* indices = (const int*)d_in[0];
  const float* qp = (const float*)d_in[1];
  const float* cpos = (const float*)d_in[2];
  const float* codes = (const float*)d_in[3];
  const void* dsp = d_in[4];

  float* out = (float*)d_out;
  float* qc = out;                                   // (B,P,D)
  float* sq = qc + (size_t)NB * NP * ND;             // (B,P,C)
  float* wt = sq + (size_t)NB * NP * NC;             // (B,P,C)

  const size_t ws_need = (size_t)NB * NC * ND * 2;   // 1 MiB
  dim3 grid(NB * (NP / TP));
  if (ws_size >= ws_need) {
    cc_pre<<<dim3(NB * 8), dim3(256), 0, stream>>>(indices, codes, (unsigned char*)d_ws);
    cc_main<true><<<grid, 256, 0, stream>>>(indices, qp, cpos, codes, dsp,
                                            (const unsigned char*)d_ws, qc, sq, wt);
  } else {
    cc_main<false><<<grid, 256, 0, stream>>>(indices, qp, cpos, codes, dsp,
                                             nullptr, qc, sq, wt);
  }
}